// Round 8
// baseline (6461.547 us; speedup 1.0000x reference)
//
#include <hip/hip_runtime.h>

// RecurrentSNN: B=256, T=1024, F=64, H=512, O=64
// out = concat(mem_rec [B,T,O], spk_rec [B,T,O]) f32.
//
// Round-8: 4-phase split; the two GEMMs become fully (b,t)-parallel kernels,
// the two scans become independent-scalar-recurrence kernels. No per-step
// barriers anywhere; no 200-float register working sets.
//  A snn_curA : cur1[row][h] (thread=row, x in 64 pinned VGPRs, W via
//               s_load_dwordx16 -> SGPR operand of v_fma; 4 waves/SIMD TLP
//               hides SMEM latency).
//  B snn_scanB: layer-1 membrane scan per (b,h); writes f32 spikes IN PLACE
//               over cur1 (each thread overwrites only its own slot after
//               reading it). 8-deep rotating prefetch.
//  C snn_coutC: cur_out[row][o] = b_out + spikes . W_out^T. t-parallel,
//               wout[64] pinned (r5/r6 recipe), row-pair processing,
//               one lgkm-barrier per 8 rows, 8-wave parallel reduce.
//  D snn_memoD: layer-2 membrane scan per (b,o); writes both outputs.
// All arithmetic chains verbatim from rounds 5-7 (absmax must be 0.04394531).
// ws: cur1/spk shared buffer + cur_out + state; nch in {4,8,16}; fused5
// fallback if ws is tiny.

namespace {
constexpr int kB = 256;
constexpr int kT = 1024;
constexpr int kF = 64;
constexpr int kH = 512;
constexpr int kO = 64;
constexpr float kBeta = 0.9f;
constexpr float kThresh = 1.0f;
}  // namespace

typedef __attribute__((ext_vector_type(16))) float f32x16;

#define PIN8(p)                                                            \
  asm volatile("" : "+v"((p)[0]), "+v"((p)[1]), "+v"((p)[2]),              \
                    "+v"((p)[3]), "+v"((p)[4]), "+v"((p)[5]),              \
                    "+v"((p)[6]), "+v"((p)[7]))

#define BARRIER() asm volatile("s_waitcnt lgkmcnt(0)\n\ts_barrier" ::: "memory")

// ======================= A: cur1 = x @ W_in^T + b_in ======================
// thread = one (b,t) row, h-quarter per blockIdx&3. W row arrives in SGPRs.
#define SW(i) ((i) < 16 ? w0[(i)] : (i) < 32 ? w1[(i)-16]                  \
             : (i) < 48 ? w2[(i)-32] : w3[(i)-48])
#define AQ(q)                                                              \
  c0 = fmaf(SW(4*(q)+0), xr[4*(q)+0], c0);                                 \
  c1 = fmaf(SW(4*(q)+1), xr[4*(q)+1], c1);                                 \
  c2 = fmaf(SW(4*(q)+2), xr[4*(q)+2], c2);                                 \
  c3 = fmaf(SW(4*(q)+3), xr[4*(q)+3], c3);

__global__ __launch_bounds__(256, 4)
void snn_curA(const float* __restrict__ x, const float* __restrict__ W_in,
              const float* __restrict__ b_in, float* __restrict__ cur1,
              int t0, int ntc, int l2ntc) {
  const int tid = threadIdx.x;
  const int rb = blockIdx.x >> 2;
  const int h0 = (blockIdx.x & 3) * 128;
  const int row = rb * 256 + tid;
  const int b = row >> l2ntc;
  const int tc = row & (ntc - 1);

  // x row resident in VGPRs for the whole kernel; pinned so the loads
  // cannot be sunk into the h-loop (round-1 pathology).
  float xr[kF];
  {
    const float4* xp = reinterpret_cast<const float4*>(
        x + ((size_t)b * kT + (size_t)(t0 + tc)) * kF);
#pragma unroll
    for (int q = 0; q < 16; ++q) {
      const float4 v = xp[q];
      xr[4*q+0] = v.x; xr[4*q+1] = v.y; xr[4*q+2] = v.z; xr[4*q+3] = v.w;
    }
  }
  PIN8(xr + 0);  PIN8(xr + 8);  PIN8(xr + 16); PIN8(xr + 24);
  PIN8(xr + 32); PIN8(xr + 40); PIN8(xr + 48); PIN8(xr + 56);

  float* cb = cur1 + (size_t)row * kH + h0;
  const float* wbase = W_in + (size_t)h0 * kF;
  const float* bbase = b_in + h0;

#pragma unroll 1
  for (int hh = 0; hh < 128; ++hh) {
    f32x16 w0, w1, w2, w3;
    const float* wp = wbase + (size_t)hh * kF;
    asm volatile("s_load_dwordx16 %0, %4, 0x0\n\t"
                 "s_load_dwordx16 %1, %4, 0x40\n\t"
                 "s_load_dwordx16 %2, %4, 0x80\n\t"
                 "s_load_dwordx16 %3, %4, 0xc0"
                 : "=&s"(w0), "=&s"(w1), "=&s"(w2), "=&s"(w3)
                 : "s"(wp));
    const float bin = bbase[hh];
    asm volatile("s_waitcnt lgkmcnt(0)"
                 : "+s"(w0), "+s"(w1), "+s"(w2), "+s"(w3) :: "memory");
    float c0 = bin, c1 = 0.0f, c2 = 0.0f, c3 = 0.0f;
    AQ(0) AQ(1) AQ(2) AQ(3) AQ(4) AQ(5) AQ(6) AQ(7)
    AQ(8) AQ(9) AQ(10) AQ(11) AQ(12) AQ(13) AQ(14) AQ(15)
    cb[hh] = (c0 + c1) + (c2 + c3);
  }
}

// ======================= B: layer-1 scan (per b,h) ========================
#define BSTEP(fk, tt)                                                      \
  do {                                                                     \
    mem1 = kBeta * mem1 + (fk) - rst1;                                     \
    const bool pr = mem1 > kThresh;                                        \
    rst1 = pr ? 1.0f : 0.0f;                                               \
    cp[(size_t)(tt) * kH] = rst1;  /* spike overwrites cur1 slot */        \
    const int tn_ = ((tt) + 8 < ntc) ? (tt) + 8 : ntc - 1;                 \
    fk = cp[(size_t)tn_ * kH];     /* prefetch (clamped ones unused) */    \
  } while (0)

__global__ __launch_bounds__(512)
void snn_scanB(float* __restrict__ cs, float* __restrict__ state,
               int t0, int ntc) {
  const int b = blockIdx.x;
  const int h = threadIdx.x;
  float* m1s = state;
  float* r1s = state + kB * kH;
  const int idx = b * kH + h;
  float mem1 = 0.0f, rst1 = 0.0f;
  if (t0 != 0) { mem1 = m1s[idx]; rst1 = r1s[idx]; }

  float* cp = cs + (size_t)b * ntc * kH + h;
  float f0 = cp[0 * (size_t)kH], f1 = cp[1 * (size_t)kH];
  float f2 = cp[2 * (size_t)kH], f3 = cp[3 * (size_t)kH];
  float f4 = cp[4 * (size_t)kH], f5 = cp[5 * (size_t)kH];
  float f6 = cp[6 * (size_t)kH], f7 = cp[7 * (size_t)kH];

#pragma unroll 1
  for (int t = 0; t < ntc; t += 8) {
    BSTEP(f0, t + 0); BSTEP(f1, t + 1); BSTEP(f2, t + 2); BSTEP(f3, t + 3);
    BSTEP(f4, t + 4); BSTEP(f5, t + 5); BSTEP(f6, t + 6); BSTEP(f7, t + 7);
  }
  m1s[idx] = mem1;
  r1s[idx] = rst1;
}

// ======================= C: cur_out = spikes @ W_out^T + b_out ============
#define CQ(A0, A1, A2, A3, v, q)                                           \
  A0 = fmaf((v).x, wout[4*(q)+0], A0);                                     \
  A1 = fmaf((v).y, wout[4*(q)+1], A1);                                     \
  A2 = fmaf((v).z, wout[4*(q)+2], A2);                                     \
  A3 = fmaf((v).w, wout[4*(q)+3], A3);

__global__ __launch_bounds__(512)
__attribute__((amdgpu_waves_per_eu(2, 2)))
void snn_coutC(const float* __restrict__ spk, const float* __restrict__ W_out,
               const float* __restrict__ b_out, float* __restrict__ cout,
               int ntc) {
  const int o = threadIdx.x & 63;
  const int s = threadIdx.x >> 6;
  const size_t row0 = (size_t)blockIdx.x * (size_t)ntc;

  __shared__ float red[2][8][8][64];  // [buf][rowInBatch][slice][o]

  float wout[64];
  {
    const float4* wov =
        reinterpret_cast<const float4*>(W_out) + o * (kH / 4) + s * 16;
#pragma unroll
    for (int q = 0; q < 16; ++q) {
      const float4 v = wov[q];
      wout[4*q+0] = v.x; wout[4*q+1] = v.y;
      wout[4*q+2] = v.z; wout[4*q+3] = v.w;
    }
  }
  float bout = b_out[o];
  PIN8(wout + 0);  PIN8(wout + 8);  PIN8(wout + 16); PIN8(wout + 24);
  PIN8(wout + 32); PIN8(wout + 40); PIN8(wout + 48); PIN8(wout + 56);
  asm volatile("" : "+v"(bout));

#pragma unroll 1
  for (int rb = 0; rb < ntc; rb += 8) {
    const int buf = (rb >> 3) & 1;
#pragma unroll 1
    for (int pp = 0; pp < 4; ++pp) {
      const size_t rA = row0 + (size_t)(rb + 2 * pp);
      const float4* pa =
          reinterpret_cast<const float4*>(spk + rA * kH + s * 64);
      const float4* pb =
          reinterpret_cast<const float4*>(spk + (rA + 1) * kH + s * 64);
      // two rows' spike slices (wave-uniform addresses)
      float4 u0 = pa[0], u1 = pa[1], u2 = pa[2], u3 = pa[3];
      float4 u4 = pa[4], u5 = pa[5], u6 = pa[6], u7 = pa[7];
      float4 u8 = pa[8], u9 = pa[9], u10 = pa[10], u11 = pa[11];
      float4 u12 = pa[12], u13 = pa[13], u14 = pa[14], u15 = pa[15];
      float4 v0 = pb[0], v1 = pb[1], v2 = pb[2], v3 = pb[3];
      float4 v4 = pb[4], v5 = pb[5], v6 = pb[6], v7 = pb[7];
      float4 v8 = pb[8], v9 = pb[9], v10 = pb[10], v11 = pb[11];
      float4 v12 = pb[12], v13 = pb[13], v14 = pb[14], v15 = pb[15];

      float a0 = 0.0f, a1 = 0.0f, a2 = 0.0f, a3 = 0.0f;
      float e0 = 0.0f, e1 = 0.0f, e2 = 0.0f, e3 = 0.0f;
      CQ(a0,a1,a2,a3, u0, 0)  CQ(e0,e1,e2,e3, v0, 0)
      CQ(a0,a1,a2,a3, u1, 1)  CQ(e0,e1,e2,e3, v1, 1)
      CQ(a0,a1,a2,a3, u2, 2)  CQ(e0,e1,e2,e3, v2, 2)
      CQ(a0,a1,a2,a3, u3, 3)  CQ(e0,e1,e2,e3, v3, 3)
      CQ(a0,a1,a2,a3, u4, 4)  CQ(e0,e1,e2,e3, v4, 4)
      CQ(a0,a1,a2,a3, u5, 5)  CQ(e0,e1,e2,e3, v5, 5)
      CQ(a0,a1,a2,a3, u6, 6)  CQ(e0,e1,e2,e3, v6, 6)
      CQ(a0,a1,a2,a3, u7, 7)  CQ(e0,e1,e2,e3, v7, 7)
      CQ(a0,a1,a2,a3, u8, 8)  CQ(e0,e1,e2,e3, v8, 8)
      CQ(a0,a1,a2,a3, u9, 9)  CQ(e0,e1,e2,e3, v9, 9)
      CQ(a0,a1,a2,a3, u10,10) CQ(e0,e1,e2,e3, v10,10)
      CQ(a0,a1,a2,a3, u11,11) CQ(e0,e1,e2,e3, v11,11)
      CQ(a0,a1,a2,a3, u12,12) CQ(e0,e1,e2,e3, v12,12)
      CQ(a0,a1,a2,a3, u13,13) CQ(e0,e1,e2,e3, v13,13)
      CQ(a0,a1,a2,a3, u14,14) CQ(e0,e1,e2,e3, v14,14)
      CQ(a0,a1,a2,a3, u15,15) CQ(e0,e1,e2,e3, v15,15)

      red[buf][2*pp+0][s][o] = (a0 + a1) + (a2 + a3);
      red[buf][2*pp+1][s][o] = (e0 + e1) + (e2 + e3);
    }
    BARRIER();  // lgkm-only: red visible; spike prefetches stay in flight
    // 8 waves reduce the 8 rows in parallel; wave s owns row rb+s.
    {
      float co = bout;
      co += red[buf][s][0][o]; co += red[buf][s][1][o];
      co += red[buf][s][2][o]; co += red[buf][s][3][o];
      co += red[buf][s][4][o]; co += red[buf][s][5][o];
      co += red[buf][s][6][o]; co += red[buf][s][7][o];
      cout[(row0 + (size_t)(rb + s)) * kO + o] = co;
    }
    // no second barrier: next batch writes the other red buffer; reuse of
    // this buffer happens only after the NEXT barrier (2-barrier separation).
  }
}

// ======================= D: layer-2 scan (per b,o) ========================
#define DSTEP(gk, tt)                                                      \
  do {                                                                     \
    memo = kBeta * memo + (gk) - rsto;                                     \
    const float so = (memo > kThresh) ? 1.0f : 0.0f;                       \
    rsto = so;                                                             \
    om[(size_t)(tt) * kO] = memo;                                          \
    os[(size_t)(tt) * kO] = so;                                            \
    const int tn_ = ((tt) + 8 < ntc) ? (tt) + 8 : ntc - 1;                 \
    gk = dp[(size_t)tn_ * kO];                                             \
  } while (0)

__global__ __launch_bounds__(64)
void snn_memoD(const float* __restrict__ cout, float* __restrict__ out,
               float* __restrict__ state, int t0, int ntc) {
  const int b = blockIdx.x;
  const int o = threadIdx.x;
  float* mos = state + 2 * kB * kH;
  float* ros = mos + kB * kO;
  const int idx = b * kO + o;
  float memo = 0.0f, rsto = 0.0f;
  if (t0 != 0) { memo = mos[idx]; rsto = ros[idx]; }

  const float* dp = cout + (size_t)b * ntc * kO + o;
  float* om = out + ((size_t)b * kT + t0) * kO + o;
  float* os = om + (size_t)kB * kT * kO;

  float g0 = dp[0 * (size_t)kO], g1 = dp[1 * (size_t)kO];
  float g2 = dp[2 * (size_t)kO], g3 = dp[3 * (size_t)kO];
  float g4 = dp[4 * (size_t)kO], g5 = dp[5 * (size_t)kO];
  float g6 = dp[6 * (size_t)kO], g7 = dp[7 * (size_t)kO];

#pragma unroll 1
  for (int t = 0; t < ntc; t += 8) {
    DSTEP(g0, t + 0); DSTEP(g1, t + 1); DSTEP(g2, t + 2); DSTEP(g3, t + 3);
    DSTEP(g4, t + 4); DSTEP(g5, t + 5); DSTEP(g6, t + 6); DSTEP(g7, t + 7);
  }
  mos[idx] = memo;
  ros[idx] = rsto;
}

// ======================= fallback (round-5, proven 1101us) ================
__global__ __launch_bounds__(256)
void warm_x_kernel(const float4* __restrict__ p, int n4) {
  float acc = 0.0f;
  for (int i = blockIdx.x * blockDim.x + threadIdx.x; i < n4;
       i += gridDim.x * blockDim.x) {
    const float4 v = p[i];
    acc += v.x + v.y + v.z + v.w;
  }
  asm volatile("" ::"v"(acc));
}

__global__ __launch_bounds__(512)
__attribute__((amdgpu_waves_per_eu(2, 2)))
void snn_fused5(const float* __restrict__ x, const float* __restrict__ W_in,
                const float* __restrict__ b_in,
                const float* __restrict__ W_out,
                const float* __restrict__ b_out, float* __restrict__ out) {
  const int b = blockIdx.x;
  const int j = threadIdx.x;
  const int o = j & 63;
  const int s = j >> 6;
  __shared__ float red[2][8][64];
  float win[kF];
  {
    const float4* wiv = reinterpret_cast<const float4*>(W_in) + j * 16;
#pragma unroll
    for (int q = 0; q < 16; ++q) {
      const float4 v = wiv[q];
      win[4 * q] = v.x; win[4 * q + 1] = v.y;
      win[4 * q + 2] = v.z; win[4 * q + 3] = v.w;
    }
  }
  float wout[64];
  {
    const float4* wov =
        reinterpret_cast<const float4*>(W_out) + o * 128 + s * 16;
#pragma unroll
    for (int q = 0; q < 16; ++q) {
      const float4 v = wov[q];
      wout[4 * q] = v.x; wout[4 * q + 1] = v.y;
      wout[4 * q + 2] = v.z; wout[4 * q + 3] = v.w;
    }
  }
  float bin_j = b_in[j];
  float bout_o = b_out[o];
  PIN8(win + 0);  PIN8(win + 8);  PIN8(win + 16); PIN8(win + 24);
  PIN8(win + 32); PIN8(win + 40); PIN8(win + 48); PIN8(win + 56);
  PIN8(wout + 0);  PIN8(wout + 8);  PIN8(wout + 16); PIN8(wout + 24);
  PIN8(wout + 32); PIN8(wout + 40); PIN8(wout + 48); PIN8(wout + 56);
  asm volatile("" : "+v"(bin_j), "+v"(bout_o));
  float mem1 = 0.0f, rst1 = 0.0f, memo = 0.0f, rsto = 0.0f;
  unsigned long long mask = 0ull;
  const float4* xv = reinterpret_cast<const float4*>(x + (size_t)b * kT * kF);
  float* out_mem = out + (size_t)b * kT * kO + o;
  float* out_spk = out_mem + (size_t)kB * kT * kO;
  float4 x0, x1, x2, x3, x4, x5, x6, x7, x8, x9, x10, x11, x12, x13, x14, x15;
#define LOADX(tt)                                                          \
  do {                                                                     \
    const float4* xp = xv + (size_t)(tt) * 16;                             \
    x0 = xp[0]; x1 = xp[1]; x2 = xp[2]; x3 = xp[3];                        \
    x4 = xp[4]; x5 = xp[5]; x6 = xp[6]; x7 = xp[7];                        \
    x8 = xp[8]; x9 = xp[9]; x10 = xp[10]; x11 = xp[11];                    \
    x12 = xp[12]; x13 = xp[13]; x14 = xp[14]; x15 = xp[15];                \
  } while (0)
#define L1Q(q)                                                             \
  c0 = fmaf(x##q.x, win[4 * q + 0], c0);                                   \
  c1 = fmaf(x##q.y, win[4 * q + 1], c1);                                   \
  c2 = fmaf(x##q.z, win[4 * q + 2], c2);                                   \
  c3 = fmaf(x##q.w, win[4 * q + 3], c3);
#define LAYER1F()                                                          \
  do {                                                                     \
    float c0 = bin_j, c1 = 0.0f, c2 = 0.0f, c3 = 0.0f;                     \
    L1Q(0) L1Q(1) L1Q(2) L1Q(3) L1Q(4) L1Q(5) L1Q(6) L1Q(7)                \
    L1Q(8) L1Q(9) L1Q(10) L1Q(11) L1Q(12) L1Q(13) L1Q(14) L1Q(15)          \
    const float cur1v = (c0 + c1) + (c2 + c3);                             \
    mem1 = kBeta * mem1 + cur1v - rst1;                                    \
    const bool p = mem1 > kThresh;                                         \
    mask = __ballot(p);                                                    \
    rst1 = p ? 1.0f : 0.0f;                                                \
  } while (0)
#define L2QS(q)                                                            \
  {                                                                        \
    const float f0 = ((mlo >> (4 * (q) + 0)) & 1u) ? 1.0f : 0.0f;          \
    const float f1 = ((mlo >> (4 * (q) + 1)) & 1u) ? 1.0f : 0.0f;          \
    const float f2 = ((mlo >> (4 * (q) + 2)) & 1u) ? 1.0f : 0.0f;          \
    const float f3 = ((mlo >> (4 * (q) + 3)) & 1u) ? 1.0f : 0.0f;          \
    a0 = fmaf(f0, wout[4 * (q) + 0], a0);                                  \
    a1 = fmaf(f1, wout[4 * (q) + 1], a1);                                  \
    a2 = fmaf(f2, wout[4 * (q) + 2], a2);                                  \
    a3 = fmaf(f3, wout[4 * (q) + 3], a3);                                  \
  }
#define L2E(acc, q, i)                                                     \
  acc = acc + __uint_as_float(                                             \
      (unsigned)__builtin_amdgcn_sbfe((int)vmhi, 4 * (q) + (i)-32, 1) &    \
      __float_as_uint(wout[4 * (q) + (i)]));
#define L2QV(q)                                                            \
  { L2E(a0, q, 0) L2E(a1, q, 1) L2E(a2, q, 2) L2E(a3, q, 3) }
#define LAYER2F(buf)                                                       \
  do {                                                                     \
    const unsigned mlo = (unsigned)mask;                                   \
    unsigned vmhi = (unsigned)(mask >> 32);                                \
    asm volatile("" : "+v"(vmhi));                                         \
    float a0 = 0.0f, a1 = 0.0f, a2 = 0.0f, a3 = 0.0f;                      \
    L2QS(0) L2QS(1) L2QS(2) L2QS(3) L2QS(4) L2QS(5) L2QS(6) L2QS(7)        \
    L2QV(8) L2QV(9) L2QV(10) L2QV(11) L2QV(12) L2QV(13) L2QV(14) L2QV(15)  \
    red[(buf)][s][o] = (a0 + a1) + (a2 + a3);                              \
  } while (0)
  LOADX(0);
  LAYER1F();
  LOADX(1);
  for (int t = 1; t < kT; ++t) {
    LAYER2F((t - 1) & 1);
    BARRIER();
    float r0, r1, r2, r3, r4, r5, r6, r7;
    const int buf = (t - 1) & 1;
    if (s == 0) {
      r0 = red[buf][0][o]; r1 = red[buf][1][o];
      r2 = red[buf][2][o]; r3 = red[buf][3][o];
      r4 = red[buf][4][o]; r5 = red[buf][5][o];
      r6 = red[buf][6][o]; r7 = red[buf][7][o];
    }
    LAYER1F();
    const int tn = (t + 1 < kT) ? (t + 1) : (kT - 1);
    LOADX(tn);
    if (s == 0) {
      float co = bout_o;
      co += r0; co += r1; co += r2; co += r3;
      co += r4; co += r5; co += r6; co += r7;
      memo = kBeta * memo + co - rsto;
      const float so = (memo > kThresh) ? 1.0f : 0.0f;
      rsto = so;
      out_mem[(t - 1) * kO] = memo;
      out_spk[(t - 1) * kO] = so;
    }
  }
  LAYER2F((kT - 1) & 1);
  BARRIER();
  if (s == 0) {
    const int buf = (kT - 1) & 1;
    float co = bout_o;
    co += red[buf][0][o]; co += red[buf][1][o];
    co += red[buf][2][o]; co += red[buf][3][o];
    co += red[buf][4][o]; co += red[buf][5][o];
    co += red[buf][6][o]; co += red[buf][7][o];
    memo = kBeta * memo + co - rsto;
    const float so = (memo > kThresh) ? 1.0f : 0.0f;
    out_mem[(kT - 1) * kO] = memo;
    out_spk[(kT - 1) * kO] = so;
  }
}

// ======================= host ==============================================
extern "C" void kernel_launch(void* const* d_in, const int* in_sizes, int n_in,
                              void* d_out, int out_size, void* d_ws,
                              size_t ws_size, hipStream_t stream) {
  const float* x = (const float*)d_in[0];
  const float* W_in = (const float*)d_in[1];
  const float* b_in = (const float*)d_in[2];
  const float* W_out = (const float*)d_in[3];
  const float* b_out = (const float*)d_in[4];
  float* out = (float*)d_out;

  const size_t state_bytes = ((size_t)2 * kB * kH + 2 * kB * kO) * 4;
  int nch = 0;
  for (int c : {4, 8, 16}) {
    const int ntc_c = kT / c;
    const size_t need =
        (size_t)kB * ntc_c * (kH + kO) * 4 + state_bytes;
    if (need <= ws_size) { nch = c; break; }
  }

  if (nch) {
    const int ntc = kT / nch;
    const int l2ntc = (ntc == 256) ? 8 : (ntc == 128) ? 7 : 6;
    float* cur1 = (float*)d_ws;                       // also spike buffer
    float* coutb = cur1 + (size_t)kB * ntc * kH;
    float* state = coutb + (size_t)kB * ntc * kO;

    const int gA = (kB * ntc / 256) * 4;
    for (int c = 0; c < nch; ++c) {
      const int t0 = c * ntc;
      hipLaunchKernelGGL(snn_curA, dim3(gA), dim3(256), 0, stream,
                         x, W_in, b_in, cur1, t0, ntc, l2ntc);
      hipLaunchKernelGGL(snn_scanB, dim3(kB), dim3(512), 0, stream,
                         cur1, state, t0, ntc);
      hipLaunchKernelGGL(snn_coutC, dim3(kB), dim3(512), 0, stream,
                         cur1, W_out, b_out, coutb, ntc);
      hipLaunchKernelGGL(snn_memoD, dim3(kB), dim3(64), 0, stream,
                         coutb, out, state, t0, ntc);
    }
  } else {
    const int n4 = kB * kT * kF / 4;
    hipLaunchKernelGGL(warm_x_kernel, dim3(1024), dim3(256), 0, stream,
                       (const float4*)x, n4);
    hipLaunchKernelGGL(snn_fused5, dim3(kB), dim3(512), 0, stream,
                       x, W_in, b_in, W_out, b_out, out);
  }
}

// Round 9
// 1170.417 us; speedup vs baseline: 5.5207x; 5.5207x over previous
//
#include <hip/hip_runtime.h>

// RecurrentSNN: B=256, T=1024, F=64, H=512, O=64
// out = concat(mem_rec [B,T,O], spk_rec [B,T,O]) f32.
//
// Round-9: keep the 4-phase split; rebuild both GEMMs on proven-clean
// memory patterns (round-8's C showed 22-78x HBM traffic inflation from
// dense bursts of wave-uniform vector loads -> banned pattern).
//  A snn_curA : block = 1 row x 512 h (8 waves). W_in[h] resident in 64
//      VGPRs/thread (per-lane gather ONCE); x row via s_load_dwordx16 ->
//      SGPR operand of v_fma (scalar cache, no LDS, no barrier).
//      128 rows/block, 4 waves/SIMD TLP.
//  B snn_scanB: layer-1 scan per (b,h), spikes overwrite cur1 in place
//      (unchanged from round 8 -- worked).
//  C snn_coutC: t-parallel layer-2. Thread j loads spk[row][j] (coalesced,
//      r6-K2's exact pattern); readlane spike-multiply (r6-proven);
//      one barrier per 8 rows; 8-wave parallel reduce; dbuf LDS.
//  D snn_memoD: layer-2 scan per (b,o) (unchanged from round 8).
// All arithmetic chains verbatim from passing rounds (absmax 0.04394531).

namespace {
constexpr int kB = 256;
constexpr int kT = 1024;
constexpr int kF = 64;
constexpr int kH = 512;
constexpr int kO = 64;
constexpr float kBeta = 0.9f;
constexpr float kThresh = 1.0f;
}  // namespace

typedef __attribute__((ext_vector_type(16))) float f32x16;

#define PIN8(p)                                                            \
  asm volatile("" : "+v"((p)[0]), "+v"((p)[1]), "+v"((p)[2]),              \
                    "+v"((p)[3]), "+v"((p)[4]), "+v"((p)[5]),              \
                    "+v"((p)[6]), "+v"((p)[7]))

#define BARRIER() asm volatile("s_waitcnt lgkmcnt(0)\n\ts_barrier" ::: "memory")

// ======================= A: cur1 = x @ W_in^T + b_in ======================
// x element i (0..63) from the four SGPR vectors (i is unroll-constant).
#define SX(i) ((i) < 16 ? sx0[(i)] : (i) < 32 ? sx1[(i)-16]                \
             : (i) < 48 ? sx2[(i)-32] : sx3[(i)-48])
#define AQ(q)                                                              \
  c0 = fmaf(SX(4*(q)+0), w[4*(q)+0], c0);                                  \
  c1 = fmaf(SX(4*(q)+1), w[4*(q)+1], c1);                                  \
  c2 = fmaf(SX(4*(q)+2), w[4*(q)+2], c2);                                  \
  c3 = fmaf(SX(4*(q)+3), w[4*(q)+3], c3);

__global__ __launch_bounds__(512)
void snn_curA(const float* __restrict__ x, const float* __restrict__ W_in,
              const float* __restrict__ b_in, float* __restrict__ cur1,
              int t0, int ntc, int l2ntc, int rpb) {
  const int l = threadIdx.x & 63;
  const int s = threadIdx.x >> 6;
  const int h = s * 64 + l;

  // W_in row h resident (per-lane gather, ONCE per kernel)
  float w[64];
  {
    const float4* wiv = reinterpret_cast<const float4*>(W_in) + h * 16;
#pragma unroll
    for (int q = 0; q < 16; ++q) {
      const float4 v = wiv[q];
      w[4*q+0] = v.x; w[4*q+1] = v.y; w[4*q+2] = v.z; w[4*q+3] = v.w;
    }
  }
  float binh = b_in[h];
  PIN8(w + 0);  PIN8(w + 8);  PIN8(w + 16); PIN8(w + 24);
  PIN8(w + 32); PIN8(w + 40); PIN8(w + 48); PIN8(w + 56);
  asm volatile("" : "+v"(binh));

  const int row0 = blockIdx.x * rpb;
#pragma unroll 1
  for (int r = 0; r < rpb; ++r) {
    const int row = row0 + r;
    const int b = row >> l2ntc;
    const int tc = row & (ntc - 1);
    const float* xp = x + ((size_t)b * kT + (size_t)(t0 + tc)) * kF;
    f32x16 sx0, sx1, sx2, sx3;
    asm volatile("s_load_dwordx16 %0, %4, 0x0\n\t"
                 "s_load_dwordx16 %1, %4, 0x40\n\t"
                 "s_load_dwordx16 %2, %4, 0x80\n\t"
                 "s_load_dwordx16 %3, %4, 0xc0"
                 : "=&s"(sx0), "=&s"(sx1), "=&s"(sx2), "=&s"(sx3)
                 : "s"(xp));
    asm volatile("s_waitcnt lgkmcnt(0)"
                 : "+s"(sx0), "+s"(sx1), "+s"(sx2), "+s"(sx3) :: "memory");
    float c0 = binh, c1 = 0.0f, c2 = 0.0f, c3 = 0.0f;
    AQ(0) AQ(1) AQ(2) AQ(3) AQ(4) AQ(5) AQ(6) AQ(7)
    AQ(8) AQ(9) AQ(10) AQ(11) AQ(12) AQ(13) AQ(14) AQ(15)
    cur1[(size_t)row * kH + h] = (c0 + c1) + (c2 + c3);
  }
}

// ======================= B: layer-1 scan (per b,h) ========================
#define BSTEP(fk, tt)                                                      \
  do {                                                                     \
    mem1 = kBeta * mem1 + (fk) - rst1;                                     \
    const bool pr = mem1 > kThresh;                                        \
    rst1 = pr ? 1.0f : 0.0f;                                               \
    cp[(size_t)(tt) * kH] = rst1;  /* spike overwrites cur1 slot */        \
    const int tn_ = ((tt) + 8 < ntc) ? (tt) + 8 : ntc - 1;                 \
    fk = cp[(size_t)tn_ * kH];     /* prefetch (clamped ones unused) */    \
  } while (0)

__global__ __launch_bounds__(512)
void snn_scanB(float* __restrict__ cs, float* __restrict__ state,
               int t0, int ntc) {
  const int b = blockIdx.x;
  const int h = threadIdx.x;
  float* m1s = state;
  float* r1s = state + kB * kH;
  const int idx = b * kH + h;
  float mem1 = 0.0f, rst1 = 0.0f;
  if (t0 != 0) { mem1 = m1s[idx]; rst1 = r1s[idx]; }

  float* cp = cs + (size_t)b * ntc * kH + h;
  float f0 = cp[0 * (size_t)kH], f1 = cp[1 * (size_t)kH];
  float f2 = cp[2 * (size_t)kH], f3 = cp[3 * (size_t)kH];
  float f4 = cp[4 * (size_t)kH], f5 = cp[5 * (size_t)kH];
  float f6 = cp[6 * (size_t)kH], f7 = cp[7 * (size_t)kH];

#pragma unroll 1
  for (int t = 0; t < ntc; t += 8) {
    BSTEP(f0, t + 0); BSTEP(f1, t + 1); BSTEP(f2, t + 2); BSTEP(f3, t + 3);
    BSTEP(f4, t + 4); BSTEP(f5, t + 5); BSTEP(f6, t + 6); BSTEP(f7, t + 7);
  }
  m1s[idx] = mem1;
  r1s[idx] = rst1;
}

// ======================= C: cur_out = spikes @ W_out^T + b_out ============
// Block = 512 threads (8 waves), 64 rows, batches of 8. Thread j loads
// spk[row][j] (coalesced, r6-K2 pattern). Wave s: lane l holds spike of
// h = s*64+l -> readlane(sp, k) = spike[s*64+k] (r6-proven). One barrier
// per 8-row batch; wave s reduces row rb+s.
#define SPK(vv, k)                                                         \
  __int_as_float(__builtin_amdgcn_readlane(__float_as_int(vv), (k)))

#define CROW(vv, rr)                                                       \
  do {                                                                     \
    float a0 = 0.0f, a1 = 0.0f, a2 = 0.0f, a3 = 0.0f;                      \
    _Pragma("unroll") for (int q = 0; q < 16; ++q) {                       \
      a0 = fmaf(SPK(vv, 4 * q + 0), wout[4 * q + 0], a0);                  \
      a1 = fmaf(SPK(vv, 4 * q + 1), wout[4 * q + 1], a1);                  \
      a2 = fmaf(SPK(vv, 4 * q + 2), wout[4 * q + 2], a2);                  \
      a3 = fmaf(SPK(vv, 4 * q + 3), wout[4 * q + 3], a3);                  \
    }                                                                      \
    red[buf][rr][s][o] = (a0 + a1) + (a2 + a3);                            \
  } while (0)

__global__ __launch_bounds__(512)
void snn_coutC(const float* __restrict__ spk, const float* __restrict__ W_out,
               const float* __restrict__ b_out, float* __restrict__ cout,
               int ntc) {
  const int j = threadIdx.x;
  const int o = j & 63;
  const int s = j >> 6;
  const size_t row0 = (size_t)blockIdx.x * 64;

  __shared__ float red[2][8][8][64];  // [buf][rowInBatch][slice][o]

  float wout[64];
  {
    const float4* wov =
        reinterpret_cast<const float4*>(W_out) + o * (kH / 4) + s * 16;
#pragma unroll
    for (int q = 0; q < 16; ++q) {
      const float4 v = wov[q];
      wout[4*q+0] = v.x; wout[4*q+1] = v.y;
      wout[4*q+2] = v.z; wout[4*q+3] = v.w;
    }
  }
  float bout = b_out[o];
  PIN8(wout + 0);  PIN8(wout + 8);  PIN8(wout + 16); PIN8(wout + 24);
  PIN8(wout + 32); PIN8(wout + 40); PIN8(wout + 48); PIN8(wout + 56);
  asm volatile("" : "+v"(bout));

  const float* sb = spk + row0 * kH + j;  // thread j reads h=j of each row

#pragma unroll 1
  for (int rb = 0; rb < 64; rb += 8) {
    const int buf = (rb >> 3) & 1;
    // coalesced per-lane loads: 8 rows' spike value at h=j
    float p0 = sb[(size_t)(rb + 0) * kH], p1 = sb[(size_t)(rb + 1) * kH];
    float p2 = sb[(size_t)(rb + 2) * kH], p3 = sb[(size_t)(rb + 3) * kH];
    float p4 = sb[(size_t)(rb + 4) * kH], p5 = sb[(size_t)(rb + 5) * kH];
    float p6 = sb[(size_t)(rb + 6) * kH], p7 = sb[(size_t)(rb + 7) * kH];

    CROW(p0, 0); CROW(p1, 1); CROW(p2, 2); CROW(p3, 3);
    CROW(p4, 4); CROW(p5, 5); CROW(p6, 6); CROW(p7, 7);

    BARRIER();  // red visible; single barrier per batch (dbuf separation)

    // wave s reduces row rb+s and stores (coalesced 256B)
    float co = bout;
    co += red[buf][s][0][o]; co += red[buf][s][1][o];
    co += red[buf][s][2][o]; co += red[buf][s][3][o];
    co += red[buf][s][4][o]; co += red[buf][s][5][o];
    co += red[buf][s][6][o]; co += red[buf][s][7][o];
    cout[(row0 + (size_t)(rb + s)) * kO + o] = co;
  }
}

// ======================= D: layer-2 scan (per b,o) ========================
#define DSTEP(gk, tt)                                                      \
  do {                                                                     \
    memo = kBeta * memo + (gk) - rsto;                                     \
    const float so = (memo > kThresh) ? 1.0f : 0.0f;                       \
    rsto = so;                                                             \
    om[(size_t)(tt) * kO] = memo;                                          \
    os[(size_t)(tt) * kO] = so;                                            \
    const int tn_ = ((tt) + 8 < ntc) ? (tt) + 8 : ntc - 1;                 \
    gk = dp[(size_t)tn_ * kO];                                             \
  } while (0)

__global__ __launch_bounds__(64)
void snn_memoD(const float* __restrict__ cout, float* __restrict__ out,
               float* __restrict__ state, int t0, int ntc) {
  const int b = blockIdx.x;
  const int o = threadIdx.x;
  float* mos = state + 2 * kB * kH;
  float* ros = mos + kB * kO;
  const int idx = b * kO + o;
  float memo = 0.0f, rsto = 0.0f;
  if (t0 != 0) { memo = mos[idx]; rsto = ros[idx]; }

  const float* dp = cout + (size_t)b * ntc * kO + o;
  float* om = out + ((size_t)b * kT + t0) * kO + o;
  float* os = om + (size_t)kB * kT * kO;

  float g0 = dp[0 * (size_t)kO], g1 = dp[1 * (size_t)kO];
  float g2 = dp[2 * (size_t)kO], g3 = dp[3 * (size_t)kO];
  float g4 = dp[4 * (size_t)kO], g5 = dp[5 * (size_t)kO];
  float g6 = dp[6 * (size_t)kO], g7 = dp[7 * (size_t)kO];

#pragma unroll 1
  for (int t = 0; t < ntc; t += 8) {
    DSTEP(g0, t + 0); DSTEP(g1, t + 1); DSTEP(g2, t + 2); DSTEP(g3, t + 3);
    DSTEP(g4, t + 4); DSTEP(g5, t + 5); DSTEP(g6, t + 6); DSTEP(g7, t + 7);
  }
  mos[idx] = memo;
  ros[idx] = rsto;
}

// ======================= fallback (round-5, proven 1101us) ================
__global__ __launch_bounds__(256)
void warm_x_kernel(const float4* __restrict__ p, int n4) {
  float acc = 0.0f;
  for (int i = blockIdx.x * blockDim.x + threadIdx.x; i < n4;
       i += gridDim.x * blockDim.x) {
    const float4 v = p[i];
    acc += v.x + v.y + v.z + v.w;
  }
  asm volatile("" ::"v"(acc));
}

__global__ __launch_bounds__(512)
__attribute__((amdgpu_waves_per_eu(2, 2)))
void snn_fused5(const float* __restrict__ x, const float* __restrict__ W_in,
                const float* __restrict__ b_in,
                const float* __restrict__ W_out,
                const float* __restrict__ b_out, float* __restrict__ out) {
  const int b = blockIdx.x;
  const int j = threadIdx.x;
  const int o = j & 63;
  const int s = j >> 6;
  __shared__ float red[2][8][64];
  float win[kF];
  {
    const float4* wiv = reinterpret_cast<const float4*>(W_in) + j * 16;
#pragma unroll
    for (int q = 0; q < 16; ++q) {
      const float4 v = wiv[q];
      win[4 * q] = v.x; win[4 * q + 1] = v.y;
      win[4 * q + 2] = v.z; win[4 * q + 3] = v.w;
    }
  }
  float wout[64];
  {
    const float4* wov =
        reinterpret_cast<const float4*>(W_out) + o * 128 + s * 16;
#pragma unroll
    for (int q = 0; q < 16; ++q) {
      const float4 v = wov[q];
      wout[4 * q] = v.x; wout[4 * q + 1] = v.y;
      wout[4 * q + 2] = v.z; wout[4 * q + 3] = v.w;
    }
  }
  float bin_j = b_in[j];
  float bout_o = b_out[o];
  PIN8(win + 0);  PIN8(win + 8);  PIN8(win + 16); PIN8(win + 24);
  PIN8(win + 32); PIN8(win + 40); PIN8(win + 48); PIN8(win + 56);
  PIN8(wout + 0);  PIN8(wout + 8);  PIN8(wout + 16); PIN8(wout + 24);
  PIN8(wout + 32); PIN8(wout + 40); PIN8(wout + 48); PIN8(wout + 56);
  asm volatile("" : "+v"(bin_j), "+v"(bout_o));
  float mem1 = 0.0f, rst1 = 0.0f, memo = 0.0f, rsto = 0.0f;
  unsigned long long mask = 0ull;
  const float4* xv = reinterpret_cast<const float4*>(x + (size_t)b * kT * kF);
  float* out_mem = out + (size_t)b * kT * kO + o;
  float* out_spk = out_mem + (size_t)kB * kT * kO;
  float4 x0, x1, x2, x3, x4, x5, x6, x7, x8, x9, x10, x11, x12, x13, x14, x15;
#define LOADX(tt)                                                          \
  do {                                                                     \
    const float4* xp = xv + (size_t)(tt) * 16;                             \
    x0 = xp[0]; x1 = xp[1]; x2 = xp[2]; x3 = xp[3];                        \
    x4 = xp[4]; x5 = xp[5]; x6 = xp[6]; x7 = xp[7];                        \
    x8 = xp[8]; x9 = xp[9]; x10 = xp[10]; x11 = xp[11];                    \
    x12 = xp[12]; x13 = xp[13]; x14 = xp[14]; x15 = xp[15];                \
  } while (0)
#define L1Q(q)                                                             \
  c0 = fmaf(x##q.x, win[4 * q + 0], c0);                                   \
  c1 = fmaf(x##q.y, win[4 * q + 1], c1);                                   \
  c2 = fmaf(x##q.z, win[4 * q + 2], c2);                                   \
  c3 = fmaf(x##q.w, win[4 * q + 3], c3);
#define LAYER1F()                                                          \
  do {                                                                     \
    float c0 = bin_j, c1 = 0.0f, c2 = 0.0f, c3 = 0.0f;                     \
    L1Q(0) L1Q(1) L1Q(2) L1Q(3) L1Q(4) L1Q(5) L1Q(6) L1Q(7)                \
    L1Q(8) L1Q(9) L1Q(10) L1Q(11) L1Q(12) L1Q(13) L1Q(14) L1Q(15)          \
    const float cur1v = (c0 + c1) + (c2 + c3);                             \
    mem1 = kBeta * mem1 + cur1v - rst1;                                    \
    const bool p = mem1 > kThresh;                                         \
    mask = __ballot(p);                                                    \
    rst1 = p ? 1.0f : 0.0f;                                                \
  } while (0)
#define L2QS(q)                                                            \
  {                                                                        \
    const float f0 = ((mlo >> (4 * (q) + 0)) & 1u) ? 1.0f : 0.0f;          \
    const float f1 = ((mlo >> (4 * (q) + 1)) & 1u) ? 1.0f : 0.0f;          \
    const float f2 = ((mlo >> (4 * (q) + 2)) & 1u) ? 1.0f : 0.0f;          \
    const float f3 = ((mlo >> (4 * (q) + 3)) & 1u) ? 1.0f : 0.0f;          \
    a0 = fmaf(f0, wout[4 * (q) + 0], a0);                                  \
    a1 = fmaf(f1, wout[4 * (q) + 1], a1);                                  \
    a2 = fmaf(f2, wout[4 * (q) + 2], a2);                                  \
    a3 = fmaf(f3, wout[4 * (q) + 3], a3);                                  \
  }
#define L2E(acc, q, i)                                                     \
  acc = acc + __uint_as_float(                                             \
      (unsigned)__builtin_amdgcn_sbfe((int)vmhi, 4 * (q) + (i)-32, 1) &    \
      __float_as_uint(wout[4 * (q) + (i)]));
#define L2QV(q)                                                            \
  { L2E(a0, q, 0) L2E(a1, q, 1) L2E(a2, q, 2) L2E(a3, q, 3) }
#define LAYER2F(buf)                                                       \
  do {                                                                     \
    const unsigned mlo = (unsigned)mask;                                   \
    unsigned vmhi = (unsigned)(mask >> 32);                                \
    asm volatile("" : "+v"(vmhi));                                         \
    float a0 = 0.0f, a1 = 0.0f, a2 = 0.0f, a3 = 0.0f;                      \
    L2QS(0) L2QS(1) L2QS(2) L2QS(3) L2QS(4) L2QS(5) L2QS(6) L2QS(7)        \
    L2QV(8) L2QV(9) L2QV(10) L2QV(11) L2QV(12) L2QV(13) L2QV(14) L2QV(15)  \
    red[(buf)][s][o] = (a0 + a1) + (a2 + a3);                              \
  } while (0)
  LOADX(0);
  LAYER1F();
  LOADX(1);
  for (int t = 1; t < kT; ++t) {
    LAYER2F((t - 1) & 1);
    BARRIER();
    float r0, r1, r2, r3, r4, r5, r6, r7;
    const int buf = (t - 1) & 1;
    if (s == 0) {
      r0 = red[buf][0][o]; r1 = red[buf][1][o];
      r2 = red[buf][2][o]; r3 = red[buf][3][o];
      r4 = red[buf][4][o]; r5 = red[buf][5][o];
      r6 = red[buf][6][o]; r7 = red[buf][7][o];
    }
    LAYER1F();
    const int tn = (t + 1 < kT) ? (t + 1) : (kT - 1);
    LOADX(tn);
    if (s == 0) {
      float co = bout_o;
      co += r0; co += r1; co += r2; co += r3;
      co += r4; co += r5; co += r6; co += r7;
      memo = kBeta * memo + co - rsto;
      const float so = (memo > kThresh) ? 1.0f : 0.0f;
      rsto = so;
      out_mem[(t - 1) * kO] = memo;
      out_spk[(t - 1) * kO] = so;
    }
  }
  LAYER2F((kT - 1) & 1);
  BARRIER();
  if (s == 0) {
    const int buf = (kT - 1) & 1;
    float co = bout_o;
    co += red[buf][0][o]; co += red[buf][1][o];
    co += red[buf][2][o]; co += red[buf][3][o];
    co += red[buf][4][o]; co += red[buf][5][o];
    co += red[buf][6][o]; co += red[buf][7][o];
    memo = kBeta * memo + co - rsto;
    const float so = (memo > kThresh) ? 1.0f : 0.0f;
    out_mem[(kT - 1) * kO] = memo;
    out_spk[(kT - 1) * kO] = so;
  }
}

// ======================= host ==============================================
extern "C" void kernel_launch(void* const* d_in, const int* in_sizes, int n_in,
                              void* d_out, int out_size, void* d_ws,
                              size_t ws_size, hipStream_t stream) {
  const float* x = (const float*)d_in[0];
  const float* W_in = (const float*)d_in[1];
  const float* b_in = (const float*)d_in[2];
  const float* W_out = (const float*)d_in[3];
  const float* b_out = (const float*)d_in[4];
  float* out = (float*)d_out;

  const size_t state_bytes = ((size_t)2 * kB * kH + 2 * kB * kO) * 4;
  int nch = 0;
  for (int c : {4, 8, 16}) {
    const int ntc_c = kT / c;
    const size_t need = (size_t)kB * ntc_c * (kH + kO) * 4 + state_bytes;
    if (need <= ws_size) { nch = c; break; }
  }

  if (nch) {
    const int ntc = kT / nch;
    const int l2ntc = (ntc == 256) ? 8 : (ntc == 128) ? 7 : 6;
    float* cur1 = (float*)d_ws;                       // also spike buffer
    float* coutb = cur1 + (size_t)kB * ntc * kH;
    float* state = coutb + (size_t)kB * ntc * kO;

    const int rows = kB * ntc;         // rows per chunk
    const int rpbA = 128;              // rows per A-block
    const int gA = rows / rpbA;        // 512 at nch=4
    const int gC = rows / 64;          // 1024 at nch=4

    for (int c = 0; c < nch; ++c) {
      const int t0 = c * ntc;
      hipLaunchKernelGGL(snn_curA, dim3(gA), dim3(512), 0, stream,
                         x, W_in, b_in, cur1, t0, ntc, l2ntc, rpbA);
      hipLaunchKernelGGL(snn_scanB, dim3(kB), dim3(512), 0, stream,
                         cur1, state, t0, ntc);
      hipLaunchKernelGGL(snn_coutC, dim3(gC), dim3(512), 0, stream,
                         cur1, W_out, b_out, coutb, ntc);
      hipLaunchKernelGGL(snn_memoD, dim3(kB), dim3(64), 0, stream,
                         coutb, out, state, t0, ntc);
    }
  } else {
    const int n4 = kB * kT * kF / 4;
    hipLaunchKernelGGL(warm_x_kernel, dim3(1024), dim3(256), 0, stream,
                       (const float4*)x, n4);
    hipLaunchKernelGGL(snn_fused5, dim3(kB), dim3(512), 0, stream,
                       x, W_in, b_in, W_out, b_out, out);
  }
}

// Round 11
// 1027.715 us; speedup vs baseline: 6.2873x; 1.1389x over previous
//
#include <hip/hip_runtime.h>

// RecurrentSNN: B=256, T=1024, F=64, H=512, O=64
// out = concat(mem_rec [B,T,O], spk_rec [B,T,O]) f32.
//
// Round-11 = round-10 with the C compile fix: spkrow's base must be
// SGPR-addressable; s = tid>>6 is wave-uniform but the compiler can't
// prove it -> readfirstlane(s) forces the derived pointer into SGPRs
// (round-10: "s" constraint materialized v[74:75] -> invalid operand).
//
//  A snn_curA : W_in row resident in 64 VGPRs; x row via s_load_dwordx16
//      -> SGPR operand of v_fma; rpb=64 -> 4 blocks/CU, 8 waves/SIMD.
//  B snn_scanB: layer-1 scan per (b,h); spikes overwrite cur1 in place.
//  C snn_coutC: spikes via scalar pipe (4x s_load_dwordx16/row, wave-
//      uniform 256B slice), v_fma(sgpr_spike, wout[k], acc) directly;
//      one barrier per 8-row batch; 8-wave parallel reduce; dbuf LDS.
//  D snn_memoD: layer-2 scan per (b,o).
// All fma chains verbatim -> absmax must stay exactly 0.04394531.

namespace {
constexpr int kB = 256;
constexpr int kT = 1024;
constexpr int kF = 64;
constexpr int kH = 512;
constexpr int kO = 64;
constexpr float kBeta = 0.9f;
constexpr float kThresh = 1.0f;
}  // namespace

typedef __attribute__((ext_vector_type(16))) float f32x16;

#define PIN8(p)                                                            \
  asm volatile("" : "+v"((p)[0]), "+v"((p)[1]), "+v"((p)[2]),              \
                    "+v"((p)[3]), "+v"((p)[4]), "+v"((p)[5]),              \
                    "+v"((p)[6]), "+v"((p)[7]))

#define BARRIER() asm volatile("s_waitcnt lgkmcnt(0)\n\ts_barrier" ::: "memory")

// ======================= A: cur1 = x @ W_in^T + b_in ======================
#define SX(i) ((i) < 16 ? sx0[(i)] : (i) < 32 ? sx1[(i)-16]                \
             : (i) < 48 ? sx2[(i)-32] : sx3[(i)-48])
#define AQ(q)                                                              \
  c0 = fmaf(SX(4*(q)+0), w[4*(q)+0], c0);                                  \
  c1 = fmaf(SX(4*(q)+1), w[4*(q)+1], c1);                                  \
  c2 = fmaf(SX(4*(q)+2), w[4*(q)+2], c2);                                  \
  c3 = fmaf(SX(4*(q)+3), w[4*(q)+3], c3);

__global__ __launch_bounds__(512)
void snn_curA(const float* __restrict__ x, const float* __restrict__ W_in,
              const float* __restrict__ b_in, float* __restrict__ cur1,
              int t0, int ntc, int l2ntc, int rpb) {
  const int l = threadIdx.x & 63;
  const int s = threadIdx.x >> 6;
  const int h = s * 64 + l;

  // W_in row h resident (per-lane gather, ONCE per kernel)
  float w[64];
  {
    const float4* wiv = reinterpret_cast<const float4*>(W_in) + h * 16;
#pragma unroll
    for (int q = 0; q < 16; ++q) {
      const float4 v = wiv[q];
      w[4*q+0] = v.x; w[4*q+1] = v.y; w[4*q+2] = v.z; w[4*q+3] = v.w;
    }
  }
  float binh = b_in[h];
  PIN8(w + 0);  PIN8(w + 8);  PIN8(w + 16); PIN8(w + 24);
  PIN8(w + 32); PIN8(w + 40); PIN8(w + 48); PIN8(w + 56);
  asm volatile("" : "+v"(binh));

  const int row0 = blockIdx.x * rpb;
#pragma unroll 1
  for (int r = 0; r < rpb; ++r) {
    const int row = row0 + r;
    const int b = row >> l2ntc;
    const int tc = row & (ntc - 1);
    const float* xp = x + ((size_t)b * kT + (size_t)(t0 + tc)) * kF;
    f32x16 sx0, sx1, sx2, sx3;
    asm volatile("s_load_dwordx16 %0, %4, 0x0\n\t"
                 "s_load_dwordx16 %1, %4, 0x40\n\t"
                 "s_load_dwordx16 %2, %4, 0x80\n\t"
                 "s_load_dwordx16 %3, %4, 0xc0"
                 : "=&s"(sx0), "=&s"(sx1), "=&s"(sx2), "=&s"(sx3)
                 : "s"(xp));
    asm volatile("s_waitcnt lgkmcnt(0)"
                 : "+s"(sx0), "+s"(sx1), "+s"(sx2), "+s"(sx3) :: "memory");
    float c0 = binh, c1 = 0.0f, c2 = 0.0f, c3 = 0.0f;
    AQ(0) AQ(1) AQ(2) AQ(3) AQ(4) AQ(5) AQ(6) AQ(7)
    AQ(8) AQ(9) AQ(10) AQ(11) AQ(12) AQ(13) AQ(14) AQ(15)
    cur1[(size_t)row * kH + h] = (c0 + c1) + (c2 + c3);
  }
}

// ======================= B: layer-1 scan (per b,h) ========================
#define BSTEP(fk, tt)                                                      \
  do {                                                                     \
    mem1 = kBeta * mem1 + (fk) - rst1;                                     \
    const bool pr = mem1 > kThresh;                                        \
    rst1 = pr ? 1.0f : 0.0f;                                               \
    cp[(size_t)(tt) * kH] = rst1;  /* spike overwrites cur1 slot */        \
    const int tn_ = ((tt) + 8 < ntc) ? (tt) + 8 : ntc - 1;                 \
    fk = cp[(size_t)tn_ * kH];     /* prefetch (clamped ones unused) */    \
  } while (0)

__global__ __launch_bounds__(512)
void snn_scanB(float* __restrict__ cs, float* __restrict__ state,
               int t0, int ntc) {
  const int b = blockIdx.x;
  const int h = threadIdx.x;
  float* m1s = state;
  float* r1s = state + kB * kH;
  const int idx = b * kH + h;
  float mem1 = 0.0f, rst1 = 0.0f;
  if (t0 != 0) { mem1 = m1s[idx]; rst1 = r1s[idx]; }

  float* cp = cs + (size_t)b * ntc * kH + h;
  float f0 = cp[0 * (size_t)kH], f1 = cp[1 * (size_t)kH];
  float f2 = cp[2 * (size_t)kH], f3 = cp[3 * (size_t)kH];
  float f4 = cp[4 * (size_t)kH], f5 = cp[5 * (size_t)kH];
  float f6 = cp[6 * (size_t)kH], f7 = cp[7 * (size_t)kH];

#pragma unroll 1
  for (int t = 0; t < ntc; t += 8) {
    BSTEP(f0, t + 0); BSTEP(f1, t + 1); BSTEP(f2, t + 2); BSTEP(f3, t + 3);
    BSTEP(f4, t + 4); BSTEP(f5, t + 5); BSTEP(f6, t + 6); BSTEP(f7, t + 7);
  }
  m1s[idx] = mem1;
  r1s[idx] = rst1;
}

// ======================= C: cur_out = spikes @ W_out^T + b_out ============
// Block = 512 threads (8 waves), 64 rows, batches of 8. Wave s reads its
// slice's spikes (256B wave-uniform, SGPR-based address via readfirstlane)
// with 4x s_load_dwordx16 -> SGPR operand of v_fma. One barrier per 8-row
// batch; wave s reduces row rb+s; dbuf LDS.
#define SC(i) ((i) < 16 ? m0[(i)] : (i) < 32 ? m1[(i)-16]                  \
             : (i) < 48 ? m2[(i)-32] : m3[(i)-48])

#define CROW(rr)                                                           \
  do {                                                                     \
    const float* sp = spkrow + (size_t)(rr) * kH;                          \
    f32x16 m0, m1, m2, m3;                                                 \
    asm volatile("s_load_dwordx16 %0, %4, 0x0\n\t"                         \
                 "s_load_dwordx16 %1, %4, 0x40\n\t"                        \
                 "s_load_dwordx16 %2, %4, 0x80\n\t"                        \
                 "s_load_dwordx16 %3, %4, 0xc0"                            \
                 : "=&s"(m0), "=&s"(m1), "=&s"(m2), "=&s"(m3)              \
                 : "s"(sp));                                               \
    asm volatile("s_waitcnt lgkmcnt(0)"                                    \
                 : "+s"(m0), "+s"(m1), "+s"(m2), "+s"(m3) :: "memory");    \
    float a0 = 0.0f, a1 = 0.0f, a2 = 0.0f, a3 = 0.0f;                      \
    _Pragma("unroll") for (int q = 0; q < 16; ++q) {                       \
      a0 = fmaf(SC(4 * q + 0), wout[4 * q + 0], a0);                       \
      a1 = fmaf(SC(4 * q + 1), wout[4 * q + 1], a1);                       \
      a2 = fmaf(SC(4 * q + 2), wout[4 * q + 2], a2);                       \
      a3 = fmaf(SC(4 * q + 3), wout[4 * q + 3], a3);                       \
    }                                                                      \
    red[buf][rr][s][o] = (a0 + a1) + (a2 + a3);                            \
  } while (0)

__global__ __launch_bounds__(512)
void snn_coutC(const float* __restrict__ spk, const float* __restrict__ W_out,
               const float* __restrict__ b_out, float* __restrict__ cout,
               int ntc) {
  const int j = threadIdx.x;
  const int o = j & 63;
  const int s = j >> 6;
  // wave-uniform copy of s the compiler can place in an SGPR: everything
  // derived from it (spkrow) becomes scalar-addressable.
  const int s_u = __builtin_amdgcn_readfirstlane(s);
  const size_t row0 = (size_t)blockIdx.x * 64;

  __shared__ float red[2][8][8][64];  // [buf][rowInBatch][slice][o]

  float wout[64];
  {
    const float4* wov =
        reinterpret_cast<const float4*>(W_out) + o * (kH / 4) + s * 16;
#pragma unroll
    for (int q = 0; q < 16; ++q) {
      const float4 v = wov[q];
      wout[4*q+0] = v.x; wout[4*q+1] = v.y;
      wout[4*q+2] = v.z; wout[4*q+3] = v.w;
    }
  }
  float bout = b_out[o];
  PIN8(wout + 0);  PIN8(wout + 8);  PIN8(wout + 16); PIN8(wout + 24);
  PIN8(wout + 32); PIN8(wout + 40); PIN8(wout + 48); PIN8(wout + 56);
  asm volatile("" : "+v"(bout));

#pragma unroll 1
  for (int rb = 0; rb < 64; rb += 8) {
    const int buf = (rb >> 3) & 1;
    const float* spkrow = spk + (row0 + (size_t)rb) * kH + s_u * 64;

    CROW(0); CROW(1); CROW(2); CROW(3);
    CROW(4); CROW(5); CROW(6); CROW(7);

    BARRIER();  // red visible; single barrier per batch (dbuf separation)

    // wave s reduces row rb+s and stores (coalesced 256B)
    float co = bout;
    co += red[buf][s][0][o]; co += red[buf][s][1][o];
    co += red[buf][s][2][o]; co += red[buf][s][3][o];
    co += red[buf][s][4][o]; co += red[buf][s][5][o];
    co += red[buf][s][6][o]; co += red[buf][s][7][o];
    cout[(row0 + (size_t)(rb + s)) * kO + o] = co;
  }
}

// ======================= D: layer-2 scan (per b,o) ========================
#define DSTEP(gk, tt)                                                      \
  do {                                                                     \
    memo = kBeta * memo + (gk) - rsto;                                     \
    const float so = (memo > kThresh) ? 1.0f : 0.0f;                       \
    rsto = so;                                                             \
    om[(size_t)(tt) * kO] = memo;                                          \
    os[(size_t)(tt) * kO] = so;                                            \
    const int tn_ = ((tt) + 8 < ntc) ? (tt) + 8 : ntc - 1;                 \
    gk = dp[(size_t)tn_ * kO];                                             \
  } while (0)

__global__ __launch_bounds__(64)
void snn_memoD(const float* __restrict__ cout, float* __restrict__ out,
               float* __restrict__ state, int t0, int ntc) {
  const int b = blockIdx.x;
  const int o = threadIdx.x;
  float* mos = state + 2 * kB * kH;
  float* ros = mos + kB * kO;
  const int idx = b * kO + o;
  float memo = 0.0f, rsto = 0.0f;
  if (t0 != 0) { memo = mos[idx]; rsto = ros[idx]; }

  const float* dp = cout + (size_t)b * ntc * kO + o;
  float* om = out + ((size_t)b * kT + t0) * kO + o;
  float* os = om + (size_t)kB * kT * kO;

  float g0 = dp[0 * (size_t)kO], g1 = dp[1 * (size_t)kO];
  float g2 = dp[2 * (size_t)kO], g3 = dp[3 * (size_t)kO];
  float g4 = dp[4 * (size_t)kO], g5 = dp[5 * (size_t)kO];
  float g6 = dp[6 * (size_t)kO], g7 = dp[7 * (size_t)kO];

#pragma unroll 1
  for (int t = 0; t < ntc; t += 8) {
    DSTEP(g0, t + 0); DSTEP(g1, t + 1); DSTEP(g2, t + 2); DSTEP(g3, t + 3);
    DSTEP(g4, t + 4); DSTEP(g5, t + 5); DSTEP(g6, t + 6); DSTEP(g7, t + 7);
  }
  mos[idx] = memo;
  ros[idx] = rsto;
}

// ======================= fallback (round-5, proven 1101us) ================
__global__ __launch_bounds__(256)
void warm_x_kernel(const float4* __restrict__ p, int n4) {
  float acc = 0.0f;
  for (int i = blockIdx.x * blockDim.x + threadIdx.x; i < n4;
       i += gridDim.x * blockDim.x) {
    const float4 v = p[i];
    acc += v.x + v.y + v.z + v.w;
  }
  asm volatile("" ::"v"(acc));
}

__global__ __launch_bounds__(512)
__attribute__((amdgpu_waves_per_eu(2, 2)))
void snn_fused5(const float* __restrict__ x, const float* __restrict__ W_in,
                const float* __restrict__ b_in,
                const float* __restrict__ W_out,
                const float* __restrict__ b_out, float* __restrict__ out) {
  const int b = blockIdx.x;
  const int j = threadIdx.x;
  const int o = j & 63;
  const int s = j >> 6;
  __shared__ float red[2][8][64];
  float win[kF];
  {
    const float4* wiv = reinterpret_cast<const float4*>(W_in) + j * 16;
#pragma unroll
    for (int q = 0; q < 16; ++q) {
      const float4 v = wiv[q];
      win[4 * q] = v.x; win[4 * q + 1] = v.y;
      win[4 * q + 2] = v.z; win[4 * q + 3] = v.w;
    }
  }
  float wout[64];
  {
    const float4* wov =
        reinterpret_cast<const float4*>(W_out) + o * 128 + s * 16;
#pragma unroll
    for (int q = 0; q < 16; ++q) {
      const float4 v = wov[q];
      wout[4 * q] = v.x; wout[4 * q + 1] = v.y;
      wout[4 * q + 2] = v.z; wout[4 * q + 3] = v.w;
    }
  }
  float bin_j = b_in[j];
  float bout_o = b_out[o];
  PIN8(win + 0);  PIN8(win + 8);  PIN8(win + 16); PIN8(win + 24);
  PIN8(win + 32); PIN8(win + 40); PIN8(win + 48); PIN8(win + 56);
  PIN8(wout + 0);  PIN8(wout + 8);  PIN8(wout + 16); PIN8(wout + 24);
  PIN8(wout + 32); PIN8(wout + 40); PIN8(wout + 48); PIN8(wout + 56);
  asm volatile("" : "+v"(bin_j), "+v"(bout_o));
  float mem1 = 0.0f, rst1 = 0.0f, memo = 0.0f, rsto = 0.0f;
  unsigned long long mask = 0ull;
  const float4* xv = reinterpret_cast<const float4*>(x + (size_t)b * kT * kF);
  float* out_mem = out + (size_t)b * kT * kO + o;
  float* out_spk = out_mem + (size_t)kB * kT * kO;
  float4 x0, x1, x2, x3, x4, x5, x6, x7, x8, x9, x10, x11, x12, x13, x14, x15;
#define LOADX(tt)                                                          \
  do {                                                                     \
    const float4* xp = xv + (size_t)(tt) * 16;                             \
    x0 = xp[0]; x1 = xp[1]; x2 = xp[2]; x3 = xp[3];                        \
    x4 = xp[4]; x5 = xp[5]; x6 = xp[6]; x7 = xp[7];                        \
    x8 = xp[8]; x9 = xp[9]; x10 = xp[10]; x11 = xp[11];                    \
    x12 = xp[12]; x13 = xp[13]; x14 = xp[14]; x15 = xp[15];                \
  } while (0)
#define L1Q(q)                                                             \
  c0 = fmaf(x##q.x, win[4 * q + 0], c0);                                   \
  c1 = fmaf(x##q.y, win[4 * q + 1], c1);                                   \
  c2 = fmaf(x##q.z, win[4 * q + 2], c2);                                   \
  c3 = fmaf(x##q.w, win[4 * q + 3], c3);
#define LAYER1F()                                                          \
  do {                                                                     \
    float c0 = bin_j, c1 = 0.0f, c2 = 0.0f, c3 = 0.0f;                     \
    L1Q(0) L1Q(1) L1Q(2) L1Q(3) L1Q(4) L1Q(5) L1Q(6) L1Q(7)                \
    L1Q(8) L1Q(9) L1Q(10) L1Q(11) L1Q(12) L1Q(13) L1Q(14) L1Q(15)          \
    const float cur1v = (c0 + c1) + (c2 + c3);                             \
    mem1 = kBeta * mem1 + cur1v - rst1;                                    \
    const bool p = mem1 > kThresh;                                         \
    mask = __ballot(p);                                                    \
    rst1 = p ? 1.0f : 0.0f;                                                \
  } while (0)
#define L2QS(q)                                                            \
  {                                                                        \
    const float f0 = ((mlo >> (4 * (q) + 0)) & 1u) ? 1.0f : 0.0f;          \
    const float f1 = ((mlo >> (4 * (q) + 1)) & 1u) ? 1.0f : 0.0f;          \
    const float f2 = ((mlo >> (4 * (q) + 2)) & 1u) ? 1.0f : 0.0f;          \
    const float f3 = ((mlo >> (4 * (q) + 3)) & 1u) ? 1.0f : 0.0f;          \
    a0 = fmaf(f0, wout[4 * (q) + 0], a0);                                  \
    a1 = fmaf(f1, wout[4 * (q) + 1], a1);                                  \
    a2 = fmaf(f2, wout[4 * (q) + 2], a2);                                  \
    a3 = fmaf(f3, wout[4 * (q) + 3], a3);                                  \
  }
#define L2E(acc, q, i)                                                     \
  acc = acc + __uint_as_float(                                             \
      (unsigned)__builtin_amdgcn_sbfe((int)vmhi, 4 * (q) + (i)-32, 1) &    \
      __float_as_uint(wout[4 * (q) + (i)]));
#define L2QV(q)                                                            \
  { L2E(a0, q, 0) L2E(a1, q, 1) L2E(a2, q, 2) L2E(a3, q, 3) }
#define LAYER2F(buf)                                                       \
  do {                                                                     \
    const unsigned mlo = (unsigned)mask;                                   \
    unsigned vmhi = (unsigned)(mask >> 32);                                \
    asm volatile("" : "+v"(vmhi));                                         \
    float a0 = 0.0f, a1 = 0.0f, a2 = 0.0f, a3 = 0.0f;                      \
    L2QS(0) L2QS(1) L2QS(2) L2QS(3) L2QS(4) L2QS(5) L2QS(6) L2QS(7)        \
    L2QV(8) L2QV(9) L2QV(10) L2QV(11) L2QV(12) L2QV(13) L2QV(14) L2QV(15)  \
    red[(buf)][s][o] = (a0 + a1) + (a2 + a3);                              \
  } while (0)
  LOADX(0);
  LAYER1F();
  LOADX(1);
  for (int t = 1; t < kT; ++t) {
    LAYER2F((t - 1) & 1);
    BARRIER();
    float r0, r1, r2, r3, r4, r5, r6, r7;
    const int buf = (t - 1) & 1;
    if (s == 0) {
      r0 = red[buf][0][o]; r1 = red[buf][1][o];
      r2 = red[buf][2][o]; r3 = red[buf][3][o];
      r4 = red[buf][4][o]; r5 = red[buf][5][o];
      r6 = red[buf][6][o]; r7 = red[buf][7][o];
    }
    LAYER1F();
    const int tn = (t + 1 < kT) ? (t + 1) : (kT - 1);
    LOADX(tn);
    if (s == 0) {
      float co = bout_o;
      co += r0; co += r1; co += r2; co += r3;
      co += r4; co += r5; co += r6; co += r7;
      memo = kBeta * memo + co - rsto;
      const float so = (memo > kThresh) ? 1.0f : 0.0f;
      rsto = so;
      out_mem[(t - 1) * kO] = memo;
      out_spk[(t - 1) * kO] = so;
    }
  }
  LAYER2F((kT - 1) & 1);
  BARRIER();
  if (s == 0) {
    const int buf = (kT - 1) & 1;
    float co = bout_o;
    co += red[buf][0][o]; co += red[buf][1][o];
    co += red[buf][2][o]; co += red[buf][3][o];
    co += red[buf][4][o]; co += red[buf][5][o];
    co += red[buf][6][o]; co += red[buf][7][o];
    memo = kBeta * memo + co - rsto;
    const float so = (memo > kThresh) ? 1.0f : 0.0f;
    out_mem[(kT - 1) * kO] = memo;
    out_spk[(kT - 1) * kO] = so;
  }
}

// ======================= host ==============================================
extern "C" void kernel_launch(void* const* d_in, const int* in_sizes, int n_in,
                              void* d_out, int out_size, void* d_ws,
                              size_t ws_size, hipStream_t stream) {
  const float* x = (const float*)d_in[0];
  const float* W_in = (const float*)d_in[1];
  const float* b_in = (const float*)d_in[2];
  const float* W_out = (const float*)d_in[3];
  const float* b_out = (const float*)d_in[4];
  float* out = (float*)d_out;

  const size_t state_bytes = ((size_t)2 * kB * kH + 2 * kB * kO) * 4;
  int nch = 0;
  for (int c : {4, 8, 16}) {
    const int ntc_c = kT / c;
    const size_t need = (size_t)kB * ntc_c * (kH + kO) * 4 + state_bytes;
    if (need <= ws_size) { nch = c; break; }
  }

  if (nch) {
    const int ntc = kT / nch;
    const int l2ntc = (ntc == 256) ? 8 : (ntc == 128) ? 7 : 6;
    float* cur1 = (float*)d_ws;                       // also spike buffer
    float* coutb = cur1 + (size_t)kB * ntc * kH;
    float* state = coutb + (size_t)kB * ntc * kO;

    const int rows = kB * ntc;         // rows per chunk
    const int rpbA = 64;               // rows per A-block (4 blocks/CU)
    const int gA = rows / rpbA;
    const int gC = rows / 64;

    for (int c = 0; c < nch; ++c) {
      const int t0 = c * ntc;
      hipLaunchKernelGGL(snn_curA, dim3(gA), dim3(512), 0, stream,
                         x, W_in, b_in, cur1, t0, ntc, l2ntc, rpbA);
      hipLaunchKernelGGL(snn_scanB, dim3(kB), dim3(512), 0, stream,
                         cur1, state, t0, ntc);
      hipLaunchKernelGGL(snn_coutC, dim3(gC), dim3(512), 0, stream,
                         cur1, W_out, b_out, coutb, ntc);
      hipLaunchKernelGGL(snn_memoD, dim3(kB), dim3(64), 0, stream,
                         coutb, out, state, t0, ntc);
    }
  } else {
    const int n4 = kB * kT * kF / 4;
    hipLaunchKernelGGL(warm_x_kernel, dim3(1024), dim3(256), 0, stream,
                       (const float4*)x, n4);
    hipLaunchKernelGGL(snn_fused5, dim3(kB), dim3(512), 0, stream,
                       x, W_in, b_in, W_out, b_out, out);
  }
}